// Round 2
// baseline (285.810 us; speedup 1.0000x reference)
//
#include <hip/hip_runtime.h>

namespace {
constexpr int kB = 2;
constexpr int kH = 352;
constexpr int kW = 1216;
constexpr int kHW = kH * kW;        // 428032
constexpr int kN = kB * kHW;        // 856064
constexpr float kDmax = 80.0f;
constexpr float kEps = 1e-6f;
constexpr int kBlock = 256;
constexpr int kSteps = 6;
}

// Module-owned workspace: 48 merged-weight channels (7x7 minus center) + 1 Q
// channel, plus one ping buffer for the Dt ping-pong. Fully rewritten from the
// inputs on every kernel_launch (no cross-call state dependence).
__device__ float g_Wq[(size_t)49 * kN];   // ~168 MB
__device__ float g_ping[kN];              // ~3.4 MB

// Merged-weight precompute.
// W'(off) = (1-g) * sum_k sigma_k * Ak_norm(off), off != center
// Q       = (1-g) * (sum_k sigma_k * Ak_norm_center) * D0 + g * DL
// (center-tap Dt coefficient cancels exactly: Ak_c - Ak_c = 0)
__global__ __launch_bounds__(kBlock) void prep_kernel(
    const float* __restrict__ D0, const float* __restrict__ DL,
    const float* __restrict__ ML, const float* __restrict__ A3,
    const float* __restrict__ A5, const float* __restrict__ A7,
    const float* __restrict__ SG, const float* __restrict__ AL)
{
    int idx = blockIdx.x * kBlock + threadIdx.x;
    if (idx >= kN) return;
    int b = idx / kHW;
    int rem = idx - b * kHW;

    const float* a3p = A3 + (size_t)b * 9 * kHW + rem;
    const float* a5p = A5 + (size_t)b * 25 * kHW + rem;
    const float* a7p = A7 + (size_t)b * 49 * kHW + rem;
    const float* sgp = SG + (size_t)b * 3 * kHW + rem;

    float a3[9], a5[25], a7[49];
    float s3 = 0.f, s5 = 0.f, s7 = 0.f;
#pragma unroll
    for (int c = 0; c < 9; ++c)  { a3[c] = a3p[(size_t)c * kHW]; s3 += fabsf(a3[c]); }
#pragma unroll
    for (int c = 0; c < 25; ++c) { a5[c] = a5p[(size_t)c * kHW]; s5 += fabsf(a5[c]); }
#pragma unroll
    for (int c = 0; c < 49; ++c) { a7[c] = a7p[(size_t)c * kHW]; s7 += fabsf(a7[c]); }
    float inv3 = 1.f / (s3 + kEps);
    float inv5 = 1.f / (s5 + kEps);
    float inv7 = 1.f / (s7 + kEps);

    float g0 = sgp[0], g1 = sgp[kHW], g2 = sgp[2 * kHW];
    float mx = fmaxf(g0, fmaxf(g1, g2));
    float e0 = expf(g0 - mx), e1 = expf(g1 - mx), e2 = expf(g2 - mx);
    float einv = 1.f / (e0 + e1 + e2);

    float al = fminf(fmaxf(AL[idx], 0.f), 1.f);
    float m  = (ML[idx] > 0.5f) ? 1.f : 0.f;
    float g  = al * m;
    float omg = 1.f - g;

    float w3 = omg * e0 * einv * inv3;
    float w5 = omg * e1 * einv * inv5;
    float w7 = omg * e2 * einv * inv7;

    float Q = (w3 * a3[4] + w5 * a5[12] + w7 * a7[24]) * D0[idx] + g * DL[idx];

    int oi = 0;
#pragma unroll
    for (int i = 0; i < 49; ++i) {
        int dy = i / 7 - 3, dx = i % 7 - 3;
        if (dy == 0 && dx == 0) continue;
        float wv = w7 * a7[i];
        if (dy >= -2 && dy <= 2 && dx >= -2 && dx <= 2)
            wv += w5 * a5[(dy + 2) * 5 + (dx + 2)];
        if (dy >= -1 && dy <= 1 && dx >= -1 && dx <= 1)
            wv += w3 * a3[(dy + 1) * 3 + (dx + 1)];
        g_Wq[(size_t)oi * kN + idx] = wv;
        ++oi;
    }
    g_Wq[(size_t)48 * kN + idx] = Q;
}

// One propagation step, 4 pixels per thread.
// Wq reads: float4, perfectly coalesced (16 B/lane). Din: scalar reads through
// a 10-wide row window shared by the 4 pixels (D is 3.4 MB -> L2/L3 resident).
// src_g/dst_g select the module-owned ping buffer without needing its host
// address. All loops fully unrolled -> compile-time indexing only.
__global__ __launch_bounds__(kBlock) void step_kernel(
    const float* __restrict__ Din_ext, float* __restrict__ Dout_ext,
    int src_g, int dst_g)
{
    const float* Din = src_g ? g_ping : Din_ext;
    float* Dout = dst_g ? g_ping : Dout_ext;

    int t = blockIdx.x * kBlock + threadIdx.x;   // 0 .. kN/4-1
    int p = t * 4;
    int b = p / kHW;                             // kHW % 4 == 0: group stays in one batch
    int rem = p - b * kHW;
    int y = rem / kW;                            // kW % 4 == 0: group stays in one row
    int x0 = rem - y * kW;
    const float* dinb = Din + (size_t)b * kHW;

    float4 acc = *(const float4*)(&g_Wq[(size_t)48 * kN + p]);  // Q
    int oi = 0;
#pragma unroll
    for (int dy = -3; dy <= 3; ++dy) {
        int ny = y + dy;
        bool rv = (ny >= 0) && (ny < kH);
        const float* dr = dinb + ny * kW;
        float row[10];
#pragma unroll
        for (int tt = 0; tt < 10; ++tt) {
            int xx = x0 - 3 + tt;
            row[tt] = (rv && xx >= 0 && xx < kW) ? dr[xx] : 0.f;
        }
#pragma unroll
        for (int dx = -3; dx <= 3; ++dx) {
            if (dy == 0 && dx == 0) continue;    // center tap folded into Q
            float4 w = *(const float4*)(&g_Wq[(size_t)oi * kN + p]);
            acc.x = fmaf(w.x, row[dx + 3], acc.x);
            acc.y = fmaf(w.y, row[dx + 4], acc.y);
            acc.z = fmaf(w.z, row[dx + 5], acc.z);
            acc.w = fmaf(w.w, row[dx + 6], acc.w);
            ++oi;
        }
    }
    float4 o;
    o.x = fminf(fmaxf(acc.x, 0.f), kDmax);
    o.y = fminf(fmaxf(acc.y, 0.f), kDmax);
    o.z = fminf(fmaxf(acc.z, 0.f), kDmax);
    o.w = fminf(fmaxf(acc.w, 0.f), kDmax);
    *(float4*)(&Dout[p]) = o;
}

extern "C" void kernel_launch(void* const* d_in, const int* in_sizes, int n_in,
                              void* d_out, int out_size, void* d_ws, size_t ws_size,
                              hipStream_t stream) {
    const float* D0 = (const float*)d_in[0];
    const float* DL = (const float*)d_in[1];
    const float* ML = (const float*)d_in[2];
    const float* A3 = (const float*)d_in[3];
    const float* A5 = (const float*)d_in[4];
    const float* A7 = (const float*)d_in[5];
    const float* SG = (const float*)d_in[6];
    const float* AL = (const float*)d_in[7];
    float* out = (float*)d_out;

    dim3 block(kBlock);
    dim3 gridPrep(kN / kBlock);       // 3344, exact
    dim3 gridStep(kN / 4 / kBlock);   // 836, exact

    prep_kernel<<<gridPrep, block, 0, stream>>>(D0, DL, ML, A3, A5, A7, SG, AL);

    // Chain: D0 -> ping -> out -> ping -> out -> ping -> out
    step_kernel<<<gridStep, block, 0, stream>>>(D0, nullptr, 0, 1);
    step_kernel<<<gridStep, block, 0, stream>>>(nullptr, out, 1, 0);
    step_kernel<<<gridStep, block, 0, stream>>>(out, nullptr, 0, 1);
    step_kernel<<<gridStep, block, 0, stream>>>(nullptr, out, 1, 0);
    step_kernel<<<gridStep, block, 0, stream>>>(out, nullptr, 0, 1);
    step_kernel<<<gridStep, block, 0, stream>>>(nullptr, out, 1, 0);
}

// Round 3
// 270.607 us; speedup vs baseline: 1.0562x; 1.0562x over previous
//
#include <hip/hip_runtime.h>

namespace {
constexpr int kB = 2;
constexpr int kH = 352;
constexpr int kW = 1216;
constexpr int kHW = kH * kW;        // 428032
constexpr int kN = kB * kHW;        // 856064
constexpr float kDmax = 80.0f;
constexpr float kEps = 1e-6f;
constexpr int kBlock = 256;
}

typedef _Float16 half_t;
typedef __attribute__((ext_vector_type(8))) _Float16 half8;

// Module-owned workspace, fully rewritten from inputs on every launch.
// g_Wh: 48 merged-weight channels (7x7 minus center) in fp16, channel-major
//       [ch][pixel] so both prep stores and step loads are coalesced. 82 MB ->
//       fits the 256 MB L3, so steps 2..6 read it from Infinity Cache.
// g_Q : fp32 constant term (1-g)*center_coef*D0 + g*DL (fp32 for accuracy).
__device__ half_t g_Wh[(size_t)48 * kN];  // ~82 MB
__device__ float  g_Q[kN];                // ~3.4 MB
__device__ float  g_ping[kN];             // ~3.4 MB

// Merged-weight precompute. One pixel/thread; __launch_bounds__(256,2) caps
// VGPR at 256 so all 83 affinity values stay in registers (round-2 profile:
// VGPR=48 forced re-loads -> 2.4 TB/s latency-bound at VALUBusy 8%).
__global__ __launch_bounds__(kBlock, 2) void prep_kernel(
    const float* __restrict__ D0, const float* __restrict__ DL,
    const float* __restrict__ ML, const float* __restrict__ A3,
    const float* __restrict__ A5, const float* __restrict__ A7,
    const float* __restrict__ SG, const float* __restrict__ AL)
{
    int idx = blockIdx.x * kBlock + threadIdx.x;
    if (idx >= kN) return;
    int b = idx / kHW;
    int rem = idx - b * kHW;

    const float* a3p = A3 + (size_t)b * 9 * kHW + rem;
    const float* a5p = A5 + (size_t)b * 25 * kHW + rem;
    const float* a7p = A7 + (size_t)b * 49 * kHW + rem;
    const float* sgp = SG + (size_t)b * 3 * kHW + rem;

    float a3[9], a5[25], a7[49];
    float s3 = 0.f, s5 = 0.f, s7 = 0.f;
#pragma unroll
    for (int c = 0; c < 9; ++c)  { a3[c] = a3p[(size_t)c * kHW]; s3 += fabsf(a3[c]); }
#pragma unroll
    for (int c = 0; c < 25; ++c) { a5[c] = a5p[(size_t)c * kHW]; s5 += fabsf(a5[c]); }
#pragma unroll
    for (int c = 0; c < 49; ++c) { a7[c] = a7p[(size_t)c * kHW]; s7 += fabsf(a7[c]); }
    float inv3 = 1.f / (s3 + kEps);
    float inv5 = 1.f / (s5 + kEps);
    float inv7 = 1.f / (s7 + kEps);

    float g0 = sgp[0], g1 = sgp[kHW], g2 = sgp[2 * kHW];
    float mx = fmaxf(g0, fmaxf(g1, g2));
    float e0 = expf(g0 - mx), e1 = expf(g1 - mx), e2 = expf(g2 - mx);
    float einv = 1.f / (e0 + e1 + e2);

    float al = fminf(fmaxf(AL[idx], 0.f), 1.f);
    float m  = (ML[idx] > 0.5f) ? 1.f : 0.f;
    float g  = al * m;
    float omg = 1.f - g;

    float w3 = omg * e0 * einv * inv3;
    float w5 = omg * e1 * einv * inv5;
    float w7 = omg * e2 * einv * inv7;

    g_Q[idx] = (w3 * a3[4] + w5 * a5[12] + w7 * a7[24]) * D0[idx] + g * DL[idx];

    int oi = 0;
#pragma unroll
    for (int i = 0; i < 49; ++i) {
        int dy = i / 7 - 3, dx = i % 7 - 3;
        if (dy == 0 && dx == 0) continue;    // center tap's Dt coef cancels
        float wv = w7 * a7[i];
        if (dy >= -2 && dy <= 2 && dx >= -2 && dx <= 2)
            wv += w5 * a5[(dy + 2) * 5 + (dx + 2)];
        if (dy >= -1 && dy <= 1 && dx >= -1 && dx <= 1)
            wv += w3 * a3[(dy + 1) * 3 + (dx + 1)];
        g_Wh[(size_t)oi * kN + idx] = (half_t)wv;
        ++oi;
    }
}

// One propagation step, 8 pixels/thread.
// Wq loads: half8 = 16 B/lane, coalesced; Q: 2x float4. Din neighbor reads go
// through a 14-wide row window shared by the 8 pixels (D is 3.4 MB, L2-hot).
// All loops fully unrolled -> compile-time register indexing only.
__global__ __launch_bounds__(kBlock) void step_kernel(
    const float* __restrict__ Din_ext, float* __restrict__ Dout_ext,
    int src_g, int dst_g)
{
    const float* Din = src_g ? g_ping : Din_ext;
    float* Dout = dst_g ? g_ping : Dout_ext;

    int t = blockIdx.x * kBlock + threadIdx.x;   // 0 .. kN/8-1
    int p = t * 8;
    int b = p / kHW;                             // kHW % 8 == 0
    int rem = p - b * kHW;
    int y = rem / kW;                            // kW % 8 == 0: stays in one row
    int x0 = rem - y * kW;
    const float* dinb = Din + (size_t)b * kHW;

    float acc[8];
    {
        float4 q0 = *(const float4*)(&g_Q[p]);
        float4 q1 = *(const float4*)(&g_Q[p + 4]);
        acc[0] = q0.x; acc[1] = q0.y; acc[2] = q0.z; acc[3] = q0.w;
        acc[4] = q1.x; acc[5] = q1.y; acc[6] = q1.z; acc[7] = q1.w;
    }

    int oi = 0;
#pragma unroll
    for (int dy = -3; dy <= 3; ++dy) {
        int ny = y + dy;
        bool rv = (ny >= 0) && (ny < kH);
        const float* dr = dinb + ny * kW;
        float row[14];
#pragma unroll
        for (int tt = 0; tt < 14; ++tt) {
            int xx = x0 - 3 + tt;
            row[tt] = (rv && xx >= 0 && xx < kW) ? dr[xx] : 0.f;
        }
#pragma unroll
        for (int dx = -3; dx <= 3; ++dx) {
            if (dy == 0 && dx == 0) continue;
            half8 w = *(const half8*)(&g_Wh[(size_t)oi * kN + p]);
#pragma unroll
            for (int j = 0; j < 8; ++j)
                acc[j] = fmaf((float)w[j], row[dx + 3 + j], acc[j]);
            ++oi;
        }
    }
#pragma unroll
    for (int j = 0; j < 8; ++j)
        acc[j] = fminf(fmaxf(acc[j], 0.f), kDmax);
    float4 o0 = make_float4(acc[0], acc[1], acc[2], acc[3]);
    float4 o1 = make_float4(acc[4], acc[5], acc[6], acc[7]);
    *(float4*)(&Dout[p])     = o0;
    *(float4*)(&Dout[p + 4]) = o1;
}

extern "C" void kernel_launch(void* const* d_in, const int* in_sizes, int n_in,
                              void* d_out, int out_size, void* d_ws, size_t ws_size,
                              hipStream_t stream) {
    const float* D0 = (const float*)d_in[0];
    const float* DL = (const float*)d_in[1];
    const float* ML = (const float*)d_in[2];
    const float* A3 = (const float*)d_in[3];
    const float* A5 = (const float*)d_in[4];
    const float* A7 = (const float*)d_in[5];
    const float* SG = (const float*)d_in[6];
    const float* AL = (const float*)d_in[7];
    float* out = (float*)d_out;

    dim3 block(kBlock);
    dim3 gridPrep(kN / kBlock);        // 3344, exact
    dim3 gridStep(kN / 8 / kBlock);    // 418, exact

    prep_kernel<<<gridPrep, block, 0, stream>>>(D0, DL, ML, A3, A5, A7, SG, AL);

    // Chain: D0 -> ping -> out -> ping -> out -> ping -> out
    step_kernel<<<gridStep, block, 0, stream>>>(D0, nullptr, 0, 1);
    step_kernel<<<gridStep, block, 0, stream>>>(nullptr, out, 1, 0);
    step_kernel<<<gridStep, block, 0, stream>>>(out, nullptr, 0, 1);
    step_kernel<<<gridStep, block, 0, stream>>>(nullptr, out, 1, 0);
    step_kernel<<<gridStep, block, 0, stream>>>(out, nullptr, 0, 1);
    step_kernel<<<gridStep, block, 0, stream>>>(nullptr, out, 1, 0);
}

// Round 4
// 204.904 us; speedup vs baseline: 1.3948x; 1.3206x over previous
//
#include <hip/hip_runtime.h>

namespace {
constexpr int kB = 2;
constexpr int kH = 352;
constexpr int kW = 1216;
constexpr int kHW = kH * kW;        // 428032
constexpr int kN = kB * kHW;        // 856064
constexpr float kDmax = 80.0f;
constexpr float kEps = 1e-6f;
constexpr int kBlock = 256;
}

typedef _Float16 half_t;
typedef __attribute__((ext_vector_type(4))) _Float16 half4;

// Module-owned workspace, fully rewritten from inputs on every launch.
// g_Wh: 48 merged-weight channels (7x7 minus center), fp16, channel-major.
//       82 MB -> L3-resident across the 6 steps.
// g_Q : fp32 constant term (1-g)*center_coef*D0 + g*DL.
__device__ half_t g_Wh[(size_t)48 * kN];  // ~82 MB
__device__ float  g_Q[kN];                // ~3.4 MB
__device__ float  g_ping[kN];             // ~3.4 MB

// Merged-weight precompute.
// Round-3 lesson: an 83-float live set always spills (VGPR=76, 2 TB/s,
// latency-bound). Keep a3+a5 (34 floats) in regs; stream a7 once, stashing it
// in LDS as fp16 (25 KB/block -> 6 blocks/CU; per-thread-private slots, no
// barriers; 2-lanes-per-dword LDS access is conflict-free).
__global__ __launch_bounds__(kBlock) void prep_kernel(
    const float* __restrict__ D0, const float* __restrict__ DL,
    const float* __restrict__ ML, const float* __restrict__ A3,
    const float* __restrict__ A5, const float* __restrict__ A7,
    const float* __restrict__ SG, const float* __restrict__ AL)
{
    __shared__ half_t sh_a7[49 * kBlock];
    int tid = threadIdx.x;
    int idx = blockIdx.x * kBlock + tid;
    int b = idx / kHW;
    int rem = idx - b * kHW;

    const float* a3p = A3 + (size_t)b * 9 * kHW + rem;
    const float* a5p = A5 + (size_t)b * 25 * kHW + rem;
    const float* a7p = A7 + (size_t)b * 49 * kHW + rem;
    const float* sgp = SG + (size_t)b * 3 * kHW + rem;

    float a3[9], a5[25];
    float s3 = 0.f, s5 = 0.f, s7 = 0.f, c7 = 0.f;
#pragma unroll
    for (int c = 0; c < 9; ++c)  { a3[c] = a3p[(size_t)c * kHW]; s3 += fabsf(a3[c]); }
#pragma unroll
    for (int c = 0; c < 25; ++c) { a5[c] = a5p[(size_t)c * kHW]; s5 += fabsf(a5[c]); }
#pragma unroll
    for (int c = 0; c < 49; ++c) {
        float v = a7p[(size_t)c * kHW];
        s7 += fabsf(v);
        if (c == 24) c7 = v;
        sh_a7[c * kBlock + tid] = (half_t)v;
    }

    float inv3 = 1.f / (s3 + kEps);
    float inv5 = 1.f / (s5 + kEps);
    float inv7 = 1.f / (s7 + kEps);

    float g0 = sgp[0], g1 = sgp[kHW], g2 = sgp[2 * kHW];
    float mx = fmaxf(g0, fmaxf(g1, g2));
    float e0 = expf(g0 - mx), e1 = expf(g1 - mx), e2 = expf(g2 - mx);
    float einv = 1.f / (e0 + e1 + e2);

    float al = fminf(fmaxf(AL[idx], 0.f), 1.f);
    float m  = (ML[idx] > 0.5f) ? 1.f : 0.f;
    float g  = al * m;
    float omg = 1.f - g;

    float w3 = omg * e0 * einv * inv3;
    float w5 = omg * e1 * einv * inv5;
    float w7 = omg * e2 * einv * inv7;

    g_Q[idx] = (w3 * a3[4] + w5 * a5[12] + w7 * c7) * D0[idx] + g * DL[idx];

    int oi = 0;
#pragma unroll
    for (int i = 0; i < 49; ++i) {
        int dy = i / 7 - 3, dx = i % 7 - 3;
        if (dy == 0 && dx == 0) continue;    // center tap's Dt coef cancels
        float wv = w7 * (float)sh_a7[i * kBlock + tid];
        if (dy >= -2 && dy <= 2 && dx >= -2 && dx <= 2)
            wv += w5 * a5[(dy + 2) * 5 + (dx + 2)];
        if (dy >= -1 && dy <= 1 && dx >= -1 && dx <= 1)
            wv += w3 * a3[(dy + 1) * 3 + (dx + 1)];
        g_Wh[(size_t)oi * kN + idx] = (half_t)wv;
        ++oi;
    }
}

// One propagation step, 4 pixels/thread (grid 836 blocks, 3.3 waves/SIMD vs
// round-3's 1.6). Weights: half4 = 8 B/lane coalesced. Din rows: 3 float4
// segment loads per row; x0 is 4-aligned so each segment is entirely in- or
// out-of-bounds (one predicate, no per-element masking).
__global__ __launch_bounds__(kBlock) void step_kernel(
    const float* __restrict__ Din_ext, float* __restrict__ Dout_ext,
    int src_g, int dst_g)
{
    const float* Din = src_g ? g_ping : Din_ext;
    float* Dout = dst_g ? g_ping : Dout_ext;

    int t = blockIdx.x * kBlock + threadIdx.x;   // 0 .. kN/4-1
    int p = t * 4;
    int b = p / kHW;                             // kHW % 4 == 0
    int rem = p - b * kHW;
    int y = rem / kW;                            // kW % 4 == 0: stays in one row
    int x0 = rem - y * kW;
    const float* dinb = Din + (size_t)b * kHW;

    float4 q = *(const float4*)(&g_Q[p]);
    float acc[4] = {q.x, q.y, q.z, q.w};

    int oi = 0;
#pragma unroll
    for (int dy = -3; dy <= 3; ++dy) {
        int ny = y + dy;
        bool rv = (ny >= 0) && (ny < kH);
        if (!rv) { oi += (dy == 0) ? 6 : 7; continue; }   // zero contribution
        const float* dr = dinb + ny * kW;

        float rowv[12];   // covers x0-4 .. x0+7
#pragma unroll
        for (int s = 0; s < 3; ++s) {
            int xb = x0 + (s - 1) * 4;
            float4 v = (xb >= 0 && xb < kW) ? *(const float4*)(dr + xb)
                                            : make_float4(0.f, 0.f, 0.f, 0.f);
            rowv[s * 4 + 0] = v.x; rowv[s * 4 + 1] = v.y;
            rowv[s * 4 + 2] = v.z; rowv[s * 4 + 3] = v.w;
        }
#pragma unroll
        for (int dx = -3; dx <= 3; ++dx) {
            if (dy == 0 && dx == 0) continue;
            half4 w = *(const half4*)(&g_Wh[(size_t)oi * kN + p]);
#pragma unroll
            for (int j = 0; j < 4; ++j)
                acc[j] = fmaf((float)w[j], rowv[4 + j + dx], acc[j]);
            ++oi;
        }
    }

    float4 o;
    o.x = fminf(fmaxf(acc[0], 0.f), kDmax);
    o.y = fminf(fmaxf(acc[1], 0.f), kDmax);
    o.z = fminf(fmaxf(acc[2], 0.f), kDmax);
    o.w = fminf(fmaxf(acc[3], 0.f), kDmax);
    *(float4*)(&Dout[p]) = o;
}

extern "C" void kernel_launch(void* const* d_in, const int* in_sizes, int n_in,
                              void* d_out, int out_size, void* d_ws, size_t ws_size,
                              hipStream_t stream) {
    const float* D0 = (const float*)d_in[0];
    const float* DL = (const float*)d_in[1];
    const float* ML = (const float*)d_in[2];
    const float* A3 = (const float*)d_in[3];
    const float* A5 = (const float*)d_in[4];
    const float* A7 = (const float*)d_in[5];
    const float* SG = (const float*)d_in[6];
    const float* AL = (const float*)d_in[7];
    float* out = (float*)d_out;

    dim3 block(kBlock);
    dim3 gridPrep(kN / kBlock);        // 3344, exact
    dim3 gridStep(kN / 4 / kBlock);    // 836, exact

    prep_kernel<<<gridPrep, block, 0, stream>>>(D0, DL, ML, A3, A5, A7, SG, AL);

    // Chain: D0 -> ping -> out -> ping -> out -> ping -> out
    step_kernel<<<gridStep, block, 0, stream>>>(D0, nullptr, 0, 1);
    step_kernel<<<gridStep, block, 0, stream>>>(nullptr, out, 1, 0);
    step_kernel<<<gridStep, block, 0, stream>>>(out, nullptr, 0, 1);
    step_kernel<<<gridStep, block, 0, stream>>>(nullptr, out, 1, 0);
    step_kernel<<<gridStep, block, 0, stream>>>(out, nullptr, 0, 1);
    step_kernel<<<gridStep, block, 0, stream>>>(nullptr, out, 1, 0);
}

// Round 5
// 203.175 us; speedup vs baseline: 1.4067x; 1.0085x over previous
//
#include <hip/hip_runtime.h>

namespace {
constexpr int kB = 2;
constexpr int kH = 352;
constexpr int kW = 1216;
constexpr int kHW = kH * kW;        // 428032
constexpr int kN = kB * kHW;        // 856064
constexpr float kDmax = 80.0f;
constexpr float kEps = 1e-6f;
constexpr int kBlock = 256;
}

typedef _Float16 half_t;
typedef __attribute__((ext_vector_type(4))) _Float16 half4;

// Module-owned workspace, fully rewritten from inputs on every launch.
__device__ half_t g_Wh[(size_t)48 * kN];  // merged weights, fp16, ch-major (~82 MB, L3-resident)
__device__ float  g_Q[kN];                // fp32 constant term
__device__ float  g_ping[kN];             // Dt ping buffer

// Async global->LDS copy, 4 B per lane (dest = wave-uniform base + lane*4).
__device__ __forceinline__ void gload_lds4(const float* g, float* l) {
    __builtin_amdgcn_global_load_lds(
        (const __attribute__((address_space(1))) void*)g,
        (__attribute__((address_space(3))) void*)l, 4, 0, 0);
}

// Merged-weight precompute.
// Round-4 lesson: compiler serializes the 83 channel-strided loads
// (load->waitcnt->use per channel at VGPR=44 -> 2 TB/s latency-bound).
// Fix: a7's 49 channels go through global_load_lds — async, zero result
// VGPRs, ~12.5 KB in flight per wave -> HBM saturates by MLP, not occupancy.
// a3+a5 (34 floats) stay in registers (VGPR headroom via launch_bounds).
__global__ __launch_bounds__(kBlock, 3) void prep_kernel(
    const float* __restrict__ D0, const float* __restrict__ DL,
    const float* __restrict__ ML, const float* __restrict__ A3,
    const float* __restrict__ A5, const float* __restrict__ A7,
    const float* __restrict__ SG, const float* __restrict__ AL)
{
    __shared__ float sh_a7[49 * kBlock];      // 50176 B -> 3 blocks/CU
    int tid = threadIdx.x;
    int idx = blockIdx.x * kBlock + tid;      // grid exact: kN % kBlock == 0
    int b = idx / kHW;
    int rem = idx - b * kHW;
    int wave = tid >> 6;

    const float* a3p = A3 + (size_t)b * 9 * kHW + rem;
    const float* a5p = A5 + (size_t)b * 25 * kHW + rem;
    const float* a7p = A7 + (size_t)b * 49 * kHW + rem;
    const float* sgp = SG + (size_t)b * 3 * kHW + rem;

    // Phase 1: fire all 49 a7 channels async into LDS (no VGPR results).
#pragma unroll
    for (int c = 0; c < 49; ++c)
        gload_lds4(a7p + (size_t)c * kHW, &sh_a7[c * kBlock + wave * 64]);

    // Phase 2: register loads for a3/a5 + the small per-pixel inputs;
    // these overlap with the in-flight a7 asyncs.
    float a3[9], a5[25];
#pragma unroll
    for (int c = 0; c < 9; ++c)  a3[c] = a3p[(size_t)c * kHW];
#pragma unroll
    for (int c = 0; c < 25; ++c) a5[c] = a5p[(size_t)c * kHW];
    float g0 = sgp[0], g1 = sgp[kHW], g2 = sgp[2 * kHW];
    float d0 = D0[idx], dl = DL[idx], ml = ML[idx], alv = AL[idx];

    float s3 = 0.f, s5 = 0.f;
#pragma unroll
    for (int c = 0; c < 9; ++c)  s3 += fabsf(a3[c]);
#pragma unroll
    for (int c = 0; c < 25; ++c) s5 += fabsf(a5[c]);

    __syncthreads();   // drains vmcnt -> LDS a7 valid

    float s7 = 0.f, c7 = 0.f;
#pragma unroll
    for (int c = 0; c < 49; ++c) {
        float v = sh_a7[c * kBlock + tid];
        s7 += fabsf(v);
        if (c == 24) c7 = v;
    }

    float inv3 = 1.f / (s3 + kEps);
    float inv5 = 1.f / (s5 + kEps);
    float inv7 = 1.f / (s7 + kEps);

    float mx = fmaxf(g0, fmaxf(g1, g2));
    float e0 = expf(g0 - mx), e1 = expf(g1 - mx), e2 = expf(g2 - mx);
    float einv = 1.f / (e0 + e1 + e2);

    float al = fminf(fmaxf(alv, 0.f), 1.f);
    float m  = (ml > 0.5f) ? 1.f : 0.f;
    float g  = al * m;
    float omg = 1.f - g;

    float w3 = omg * e0 * einv * inv3;
    float w5 = omg * e1 * einv * inv5;
    float w7 = omg * e2 * einv * inv7;

    g_Q[idx] = (w3 * a3[4] + w5 * a5[12] + w7 * c7) * d0 + g * dl;

    int oi = 0;
#pragma unroll
    for (int i = 0; i < 49; ++i) {
        int dy = i / 7 - 3, dx = i % 7 - 3;
        if (dy == 0 && dx == 0) continue;    // center tap's Dt coef cancels
        float wv = w7 * sh_a7[i * kBlock + tid];
        if (dy >= -2 && dy <= 2 && dx >= -2 && dx <= 2)
            wv += w5 * a5[(dy + 2) * 5 + (dx + 2)];
        if (dy >= -1 && dy <= 1 && dx >= -1 && dx <= 1)
            wv += w3 * a3[(dy + 1) * 3 + (dx + 1)];
        g_Wh[(size_t)oi * kN + idx] = (half_t)wv;
        ++oi;
    }
}

// One propagation step, 4 pixels/thread (unchanged from round 4: ~13 µs).
__global__ __launch_bounds__(kBlock) void step_kernel(
    const float* __restrict__ Din_ext, float* __restrict__ Dout_ext,
    int src_g, int dst_g)
{
    const float* Din = src_g ? g_ping : Din_ext;
    float* Dout = dst_g ? g_ping : Dout_ext;

    int t = blockIdx.x * kBlock + threadIdx.x;   // 0 .. kN/4-1
    int p = t * 4;
    int b = p / kHW;                             // kHW % 4 == 0
    int rem = p - b * kHW;
    int y = rem / kW;                            // kW % 4 == 0: stays in one row
    int x0 = rem - y * kW;
    const float* dinb = Din + (size_t)b * kHW;

    float4 q = *(const float4*)(&g_Q[p]);
    float acc[4] = {q.x, q.y, q.z, q.w};

    int oi = 0;
#pragma unroll
    for (int dy = -3; dy <= 3; ++dy) {
        int ny = y + dy;
        bool rv = (ny >= 0) && (ny < kH);
        if (!rv) { oi += (dy == 0) ? 6 : 7; continue; }   // zero contribution
        const float* dr = dinb + ny * kW;

        float rowv[12];   // covers x0-4 .. x0+7
#pragma unroll
        for (int s = 0; s < 3; ++s) {
            int xb = x0 + (s - 1) * 4;
            float4 v = (xb >= 0 && xb < kW) ? *(const float4*)(dr + xb)
                                            : make_float4(0.f, 0.f, 0.f, 0.f);
            rowv[s * 4 + 0] = v.x; rowv[s * 4 + 1] = v.y;
            rowv[s * 4 + 2] = v.z; rowv[s * 4 + 3] = v.w;
        }
#pragma unroll
        for (int dx = -3; dx <= 3; ++dx) {
            if (dy == 0 && dx == 0) continue;
            half4 w = *(const half4*)(&g_Wh[(size_t)oi * kN + p]);
#pragma unroll
            for (int j = 0; j < 4; ++j)
                acc[j] = fmaf((float)w[j], rowv[4 + j + dx], acc[j]);
            ++oi;
        }
    }

    float4 o;
    o.x = fminf(fmaxf(acc[0], 0.f), kDmax);
    o.y = fminf(fmaxf(acc[1], 0.f), kDmax);
    o.z = fminf(fmaxf(acc[2], 0.f), kDmax);
    o.w = fminf(fmaxf(acc[3], 0.f), kDmax);
    *(float4*)(&Dout[p]) = o;
}

extern "C" void kernel_launch(void* const* d_in, const int* in_sizes, int n_in,
                              void* d_out, int out_size, void* d_ws, size_t ws_size,
                              hipStream_t stream) {
    const float* D0 = (const float*)d_in[0];
    const float* DL = (const float*)d_in[1];
    const float* ML = (const float*)d_in[2];
    const float* A3 = (const float*)d_in[3];
    const float* A5 = (const float*)d_in[4];
    const float* A7 = (const float*)d_in[5];
    const float* SG = (const float*)d_in[6];
    const float* AL = (const float*)d_in[7];
    float* out = (float*)d_out;

    dim3 block(kBlock);
    dim3 gridPrep(kN / kBlock);        // 3344, exact
    dim3 gridStep(kN / 4 / kBlock);    // 836, exact

    prep_kernel<<<gridPrep, block, 0, stream>>>(D0, DL, ML, A3, A5, A7, SG, AL);

    // Chain: D0 -> ping -> out -> ping -> out -> ping -> out
    step_kernel<<<gridStep, block, 0, stream>>>(D0, nullptr, 0, 1);
    step_kernel<<<gridStep, block, 0, stream>>>(nullptr, out, 1, 0);
    step_kernel<<<gridStep, block, 0, stream>>>(out, nullptr, 0, 1);
    step_kernel<<<gridStep, block, 0, stream>>>(nullptr, out, 1, 0);
    step_kernel<<<gridStep, block, 0, stream>>>(out, nullptr, 0, 1);
    step_kernel<<<gridStep, block, 0, stream>>>(nullptr, out, 1, 0);
}